// Round 15
// baseline (198.320 us; speedup 1.0000x reference)
//
#include <hip/hip_runtime.h>

#define M_TOK 8192
#define N_OUT 4096
#define K_IN  4096

#define AS1 __attribute__((address_space(1)))
#define AS3 __attribute__((address_space(3)))

typedef __attribute__((ext_vector_type(4))) int i32x4;
typedef __attribute__((ext_vector_type(16))) int i32x16;

// inline-asm ds_read_b128: invisible to compiler AA; ordering is OURS via
// counted lgkmcnt + sched_barrier(0) (rule 18).
template <int OFF>
__device__ __forceinline__ i32x4 dsri(unsigned addr) {
    i32x4 r;
    asm volatile("ds_read_b128 %0, %1 offset:%2" : "=v"(r) : "v"(addr), "n"(OFF));
    return r;
}

// ---------------- prepass 1: per-token absmax quant of x (row-major out) ----

__global__ __launch_bounds__(256) void quant_x_kernel(
    const float* __restrict__ x, signed char* __restrict__ xq,
    float* __restrict__ tok_scale)
{
    const int row = blockIdx.x;
    const float4* xr = reinterpret_cast<const float4*>(x + (size_t)row * K_IN);
    const int t = threadIdx.x;
    float4 v[4];
    float m = 0.f;
#pragma unroll
    for (int i = 0; i < 4; ++i) {
        v[i] = xr[t + 256 * i];
        m = fmaxf(m, fmaxf(fmaxf(fabsf(v[i].x), fabsf(v[i].y)),
                           fmaxf(fabsf(v[i].z), fabsf(v[i].w))));
    }
#pragma unroll
    for (int off = 32; off >= 1; off >>= 1)
        m = fmaxf(m, __shfl_xor(m, off, 64));
    __shared__ float wmax[4];
    if ((t & 63) == 0) wmax[t >> 6] = m;
    __syncthreads();
    m = fmaxf(fmaxf(wmax[0], wmax[1]), fmaxf(wmax[2], wmax[3]));
    if (t == 0) tok_scale[row] = m * (1.0f / 127.0f);
    const float inv = (m > 0.f) ? (127.0f / m) : 0.f;
    int* xqi = reinterpret_cast<int*>(xq + (size_t)row * K_IN);
#pragma unroll
    for (int i = 0; i < 4; ++i) {
        const int q0 = __float2int_rn(v[i].x * inv) & 255;
        const int q1 = __float2int_rn(v[i].y * inv) & 255;
        const int q2 = __float2int_rn(v[i].z * inv) & 255;
        const int q3 = __float2int_rn(v[i].w * inv) & 255;
        xqi[t + 256 * i] = q0 | (q1 << 8) | (q2 << 16) | (q3 << 24);
    }
}

// ---------------- prepass 1b: retile xq8 row-major -> frag-tiled -------------

__global__ __launch_bounds__(256) void retile_x_kernel(
    const signed char* __restrict__ xq8, signed char* __restrict__ xqF)
{
    __shared__ __align__(16) char lds[32768];
    const int t = threadIdx.x;
    const int rb = blockIdx.x >> 2;
    const int kc = blockIdx.x & 3;

    const size_t srcBase = (size_t)rb * 32 * K_IN + (size_t)kc * 1024;
#pragma unroll
    for (int j = 0; j < 8; ++j) {
        const int u = j * 256 + t;
        const int row = u >> 6, gc = u & 63;
        const i32x4 v = *reinterpret_cast<const i32x4*>(
            xq8 + srcBase + (size_t)row * K_IN + gc * 16);
        *reinterpret_cast<i32x4*>(
            lds + ((row * 64 + (gc ^ (row & 7))) * 16)) = v;
    }
    __syncthreads();

    const int l = t & 63;
    const int W = t >> 6;
    const int row = l & 31;
    const int hi = l >> 5;
    i32x4* dst0 = reinterpret_cast<i32x4*>(xqF) +
                  ((size_t)rb * 128 + kc * 32) * 64 + l;
#pragma unroll
    for (int i = 0; i < 8; ++i) {
        const int kfl = W * 8 + i;
        const int gc = (kfl * 2 + hi) ^ (row & 7);
        const i32x4 v = *reinterpret_cast<const i32x4*>(
            lds + ((row * 64 + gc) * 16));
        dst0[(size_t)kfl * 64] = v;
    }
}

// ---------------- prepass 2: pack Wq int32 -> int8, frag-tiled ---------------

__global__ __launch_bounds__(256) void pack_w_frag_kernel(
    const int* __restrict__ wq, signed char* __restrict__ wqF)
{
    const int t = threadIdx.x;
    const int l = t & 63;
    const int W = t >> 6;
    const int rb = blockIdx.x >> 3;
    const int pc = blockIdx.x & 7;
    const int r = rb * 32 + (l & 31);
    const int4* wr4 = reinterpret_cast<const int4*>(wq) + (size_t)r * 1024;
    i32x4* outF = reinterpret_cast<i32x4*>(wqF) + (size_t)rb * 128 * 64 + l;
#pragma unroll
    for (int q = 0; q < 4; ++q) {
        const int f = W + 4 * (pc * 4 + q);
        const int c4 = f * 8 + (l >> 5) * 4;
        i32x4 o;
#pragma unroll
        for (int j = 0; j < 4; ++j) {
            const int4 a = wr4[c4 + j];
            o[j] = (a.x & 255) | ((a.y & 255) << 8) | ((a.z & 255) << 16) | ((a.w & 255) << 24);
        }
        outF[(size_t)f * 64] = o;
    }
}

// ------- int8 GEMM R15: R14 + WAVE-GROUP PHASE SKEW --------------------------
// Evidence R9-R14: body time == MFMA + LDS-port SUM (never max). Both waves
// per SIMD are barrier-locked in the SAME block running IDENTICAL code -> MFMA
// clusters align, read bursts align, pipes alternate instead of overlapping.
// Fix: waves w<4 keep compute-first order (CL4a; RD6+stage; CL4b); waves w>=4
// issue reads first (RD6+stage; CL4a; CL4b). SIMD s hosts wave s (group0) and
// wave s+4 (group1) -> one wave feeds LDS port while the other feeds matrix
// pipe. lgkm/vmcnt are PER-WAVE: group1 counts re-derived (lgkm(8) before
// CL4a: tile T's first 4 of [T's 6 + N's 6] outstanding; lgkm(6) before CL4b).
// Barrier counts identical in both paths (127 + prologue) -> legal.
// Ring-8, stage T+7, boundary vmcnt chain: unchanged from R14 (race-audited).

#define NKT 128            // K tiles of 32
#define SLOTA 8192
#define SLOTB 8192

#define MFMA(a, b, c) c = __builtin_amdgcn_mfma_i32_32x32x32_i8(a, b, c, 0, 0, 0)

// 6 reads, order: B0,B1 (cluster1), A0,A1 (cluster1), A2,A3 (cluster2)
#define RD6(P, aA, bA)                          \
    P##_B0 = dsri<0>(bA);                       \
    P##_B1 = dsri<1024>(bA);                    \
    P##_A0 = dsri<0>(aA);                       \
    P##_A1 = dsri<1024>(aA);                    \
    P##_A2 = dsri<2048>(aA);                    \
    P##_A3 = dsri<3072>(aA);

#define CL4a(P)                                               \
    MFMA(P##_A0, P##_B0, acc00); MFMA(P##_A0, P##_B1, acc01); \
    MFMA(P##_A1, P##_B0, acc10); MFMA(P##_A1, P##_B1, acc11);

#define CL4b(P)                                               \
    MFMA(P##_A2, P##_B0, acc20); MFMA(P##_A2, P##_B1, acc21); \
    MFMA(P##_A3, P##_B0, acc30); MFMA(P##_A3, P##_B1, acc31);

// group 0: compute-first (== R14 body)
#define GBODY_C(T, C, N, DO_STAGE, VM)                                    \
    {                                                                     \
        asm volatile("s_waitcnt lgkmcnt(2)" ::: "memory");                \
        __builtin_amdgcn_sched_barrier(0);                                \
        __builtin_amdgcn_s_setprio(1);                                    \
        CL4a(C)                                                           \
        __builtin_amdgcn_s_setprio(0);                                    \
        __builtin_amdgcn_sched_barrier(0);                                \
        const unsigned aN_ = aBase + (unsigned)((((T) + 1) & 7) * SLOTA); \
        const unsigned bN_ = bBase + (unsigned)((((T) + 1) & 7) * SLOTB); \
        RD6(N, aN_, bN_)                                                  \
        if (DO_STAGE) stageAB((T) + 7);                                   \
        asm volatile("s_waitcnt lgkmcnt(6)" ::: "memory");                \
        __builtin_amdgcn_sched_barrier(0);                                \
        __builtin_amdgcn_s_setprio(1);                                    \
        CL4b(C)                                                           \
        __builtin_amdgcn_s_setprio(0);                                    \
        __builtin_amdgcn_sched_barrier(0);                                \
        asm volatile("s_waitcnt vmcnt(" #VM ")" ::: "memory");            \
        __builtin_amdgcn_sched_barrier(0);                                \
        __builtin_amdgcn_s_barrier();                                     \
        __builtin_amdgcn_sched_barrier(0);                                \
    }

// group 1: reads-first. At entry: 6 outstanding (tile T's). After RD6: 12.
// lgkm(8) -> T's B0,B1,A0,A1 done (leaves T's A2,A3 + N's 6).
// lgkm(6) -> T's A2,A3 done (leaves N's 6).
#define GBODY_R(T, C, N, DO_STAGE, VM)                                    \
    {                                                                     \
        const unsigned aN_ = aBase + (unsigned)((((T) + 1) & 7) * SLOTA); \
        const unsigned bN_ = bBase + (unsigned)((((T) + 1) & 7) * SLOTB); \
        RD6(N, aN_, bN_)                                                  \
        if (DO_STAGE) stageAB((T) + 7);                                   \
        asm volatile("s_waitcnt lgkmcnt(8)" ::: "memory");                \
        __builtin_amdgcn_sched_barrier(0);                                \
        __builtin_amdgcn_s_setprio(1);                                    \
        CL4a(C)                                                           \
        __builtin_amdgcn_s_setprio(0);                                    \
        __builtin_amdgcn_sched_barrier(0);                                \
        asm volatile("s_waitcnt lgkmcnt(6)" ::: "memory");                \
        __builtin_amdgcn_sched_barrier(0);                                \
        __builtin_amdgcn_s_setprio(1);                                    \
        CL4b(C)                                                           \
        __builtin_amdgcn_s_setprio(0);                                    \
        __builtin_amdgcn_sched_barrier(0);                                \
        asm volatile("s_waitcnt vmcnt(" #VM ")" ::: "memory");            \
        __builtin_amdgcn_sched_barrier(0);                                \
        __builtin_amdgcn_s_barrier();                                     \
        __builtin_amdgcn_sched_barrier(0);                                \
    }

// final tile: no new reads; identical counts valid for both groups
// (entry outstanding = 6 = last tile's reads).
#define GFINAL(C)                                                         \
    {                                                                     \
        asm volatile("s_waitcnt lgkmcnt(2)" ::: "memory");                \
        __builtin_amdgcn_sched_barrier(0);                                \
        __builtin_amdgcn_s_setprio(1);                                    \
        CL4a(C)                                                           \
        __builtin_amdgcn_s_setprio(0);                                    \
        asm volatile("s_waitcnt lgkmcnt(0)" ::: "memory");                \
        __builtin_amdgcn_sched_barrier(0);                                \
        __builtin_amdgcn_s_setprio(1);                                    \
        CL4b(C)                                                           \
        __builtin_amdgcn_s_setprio(0);                                    \
        __builtin_amdgcn_sched_barrier(0);                                \
    }

__global__ __launch_bounds__(512, 2) void qgemm_i8sk_kernel(
    const signed char* __restrict__ xqF,
    const signed char* __restrict__ wqF,
    const float* __restrict__ tok_scale,
    const float* __restrict__ row_scales,
    const float* __restrict__ bias,
    float* __restrict__ out)
{
    __shared__ __align__(16) char smem[131072];  // A [0,64K): 8 x 8KB; B [64K,128K): 8 x 8KB

    const int tid = threadIdx.x;
    const int l = tid & 63;
    const int w = tid >> 6;      // 0..7
    const int wr = w >> 2;       // 0..1
    const int wc = w & 3;        // 0..3

    // XCD-aware bijective swizzle (nwg = 512, 512 % 8 == 0)
    const int bid = blockIdx.x;
    const int swz = (bid & 7) * 64 + (bid >> 3);
    const int bm = swz >> 4;     // 0..31
    const int bn = swz & 15;     // 0..15

    // ---- staging: wave w stages A frag w and B frag w of each tile ----
    const signed char* aS = xqF + ((size_t)(bm * 8 + w) * 128) * 1024 + (size_t)l * 16;
    const signed char* bS = wqF + ((size_t)(bn * 8 + w) * 128) * 1024 + (size_t)l * 16;
    char* aDst = smem + w * 1024;
    char* bDst = smem + 65536 + w * 1024;

    auto stageAB = [&](int tt) {
        __builtin_amdgcn_global_load_lds(
            (const AS1 void*)(aS + (size_t)tt * 1024),
            (AS3 void*)(aDst + (tt & 7) * SLOTA), 16, 0, 0);
        __builtin_amdgcn_global_load_lds(
            (const AS1 void*)(bS + (size_t)tt * 1024),
            (AS3 void*)(bDst + (tt & 7) * SLOTB), 16, 0, 0);
    };

    // ---- fragment-linear ds_read bases ----
    const unsigned sbase = (unsigned)(uintptr_t)(AS3 char*)smem;
    const unsigned aBase = sbase + (unsigned)(wr * 4096 + l * 16);            // + slot + mb*1024
    const unsigned bBase = sbase + 65536u + (unsigned)(wc * 2048 + l * 16);   // + slot + nb*1024

    i32x16 acc00 = {0}, acc01 = {0}, acc10 = {0}, acc11 = {0};
    i32x16 acc20 = {0}, acc21 = {0}, acc30 = {0}, acc31 = {0};

    i32x4 X_A0, X_A1, X_A2, X_A3, X_B0, X_B1;
    i32x4 Y_A0, Y_A1, Y_A2, Y_A3, Y_B0, Y_B1;

    // ---- prologue: stage tiles 0..6 (14 glds); vmcnt(10) confirms tiles 0,1 ----
    stageAB(0); stageAB(1); stageAB(2); stageAB(3);
    stageAB(4); stageAB(5); stageAB(6);
    asm volatile("s_waitcnt vmcnt(10)" ::: "memory");
    __builtin_amdgcn_sched_barrier(0);
    __builtin_amdgcn_s_barrier();
    __builtin_amdgcn_sched_barrier(0);
    RD6(X, aBase, bBase)

    // ---- main loop, wave-group skewed (equal barrier counts both paths) ----
    if (w < 4) {
        for (int t = 0; t < 120; t += 2) {
            GBODY_C(t,     X, Y, true, 10);
            GBODY_C(t + 1, Y, X, true, 10);
        }
        GBODY_C(120, X, Y, true, 10);   // stages tile 127 (the last)
        GBODY_C(121, Y, X, false, 8);
        GBODY_C(122, X, Y, false, 6);
        GBODY_C(123, Y, X, false, 4);
        GBODY_C(124, X, Y, false, 2);
        GBODY_C(125, Y, X, false, 0);
        GBODY_C(126, X, Y, false, 0);
    } else {
        for (int t = 0; t < 120; t += 2) {
            GBODY_R(t,     X, Y, true, 10);
            GBODY_R(t + 1, Y, X, true, 10);
        }
        GBODY_R(120, X, Y, true, 10);
        GBODY_R(121, Y, X, false, 8);
        GBODY_R(122, X, Y, false, 6);
        GBODY_R(123, Y, X, false, 4);
        GBODY_R(124, X, Y, false, 2);
        GBODY_R(125, Y, X, false, 0);
        GBODY_R(126, X, Y, false, 0);
    }
    GFINAL(Y)

    // ---- epilogue: dequant (tok_scale via global, L2-hot), store ----
    const int cl = l & 31;
    const int rg4 = (l >> 5) * 4;
    const int gcol0 = bn * 256 + wc * 64;
    const float* tsrow = tok_scale + bm * 256 + wr * 128;
    float cs[2], bb[2];
#pragma unroll
    for (int nb = 0; nb < 2; ++nb) {
        const int col = gcol0 + nb * 32 + cl;
        cs[nb] = row_scales[col] * (1.0f / 127.0f);
        bb[nb] = bias[col];
    }
    const i32x16* accs[4][2] = {{&acc00, &acc01}, {&acc10, &acc11},
                                {&acc20, &acc21}, {&acc30, &acc31}};
#pragma unroll
    for (int mb = 0; mb < 4; ++mb) {
#pragma unroll
        for (int reg = 0; reg < 16; ++reg) {
            const int rloc = wr * 128 + mb * 32 + (reg & 3) + 8 * (reg >> 2) + rg4;
            const float tsv = tsrow[mb * 32 + (reg & 3) + 8 * (reg >> 2) + rg4];
            float* orow = out + (size_t)(bm * 256 + rloc) * N_OUT + gcol0 + cl;
#pragma unroll
            for (int nb = 0; nb < 2; ++nb) {
                const int a = (*accs[mb][nb])[reg];
                orow[nb * 32] = (float)a * tsv * cs[nb] + bb[nb];
            }
        }
    }
}

// ---------------- launch ----------------

extern "C" void kernel_launch(void* const* d_in, const int* in_sizes, int n_in,
                              void* d_out, int out_size, void* d_ws, size_t ws_size,
                              hipStream_t stream) {
    const float* x = (const float*)d_in[0];
    const int* wq = (const int*)d_in[1];
    const float* row_scales = (const float*)d_in[2];
    const float* bias = (const float*)d_in[3];
    float* out = (float*)d_out;

    signed char* xq8 = (signed char*)d_ws;                       // 32 MiB row-major
    signed char* xqF = xq8 + (size_t)M_TOK * K_IN;               // 32 MiB frag-tiled
    signed char* wqF = xqF + (size_t)M_TOK * K_IN;               // 16 MiB frag-tiled
    float* tok_scale = (float*)(wqF + (size_t)N_OUT * K_IN);     // 32 KiB
    (void)ws_size;

    quant_x_kernel<<<M_TOK, 256, 0, stream>>>(x, xq8, tok_scale);
    pack_w_frag_kernel<<<1024, 256, 0, stream>>>(wq, wqF);
    retile_x_kernel<<<1024, 256, 0, stream>>>(xq8, xqF);

    const int nblocks = (M_TOK / 256) * (N_OUT / 256);  // 512
    qgemm_i8sk_kernel<<<nblocks, 512, 0, stream>>>(
        xqF, wqF, tok_scale, row_scales, bias, out);
}

// Round 16
// 197.680 us; speedup vs baseline: 1.0032x; 1.0032x over previous
//
#include <hip/hip_runtime.h>

#define M_TOK 8192
#define N_OUT 4096
#define K_IN  4096

#define AS1 __attribute__((address_space(1)))
#define AS3 __attribute__((address_space(3)))

typedef __attribute__((ext_vector_type(4))) int i32x4;
typedef __attribute__((ext_vector_type(16))) int i32x16;

// inline-asm ds_read_b128: invisible to compiler AA; ordering is OURS via
// counted lgkmcnt + sched_barrier(0) (rule 18).
template <int OFF>
__device__ __forceinline__ i32x4 dsri(unsigned addr) {
    i32x4 r;
    asm volatile("ds_read_b128 %0, %1 offset:%2" : "=v"(r) : "v"(addr), "n"(OFF));
    return r;
}

// ---------------- prepass 1: per-token absmax quant of x (row-major out) ----

__global__ __launch_bounds__(256) void quant_x_kernel(
    const float* __restrict__ x, signed char* __restrict__ xq,
    float* __restrict__ tok_scale)
{
    const int row = blockIdx.x;
    const float4* xr = reinterpret_cast<const float4*>(x + (size_t)row * K_IN);
    const int t = threadIdx.x;
    float4 v[4];
    float m = 0.f;
#pragma unroll
    for (int i = 0; i < 4; ++i) {
        v[i] = xr[t + 256 * i];
        m = fmaxf(m, fmaxf(fmaxf(fabsf(v[i].x), fabsf(v[i].y)),
                           fmaxf(fabsf(v[i].z), fabsf(v[i].w))));
    }
#pragma unroll
    for (int off = 32; off >= 1; off >>= 1)
        m = fmaxf(m, __shfl_xor(m, off, 64));
    __shared__ float wmax[4];
    if ((t & 63) == 0) wmax[t >> 6] = m;
    __syncthreads();
    m = fmaxf(fmaxf(wmax[0], wmax[1]), fmaxf(wmax[2], wmax[3]));
    if (t == 0) tok_scale[row] = m * (1.0f / 127.0f);
    const float inv = (m > 0.f) ? (127.0f / m) : 0.f;
    int* xqi = reinterpret_cast<int*>(xq + (size_t)row * K_IN);
#pragma unroll
    for (int i = 0; i < 4; ++i) {
        const int q0 = __float2int_rn(v[i].x * inv) & 255;
        const int q1 = __float2int_rn(v[i].y * inv) & 255;
        const int q2 = __float2int_rn(v[i].z * inv) & 255;
        const int q3 = __float2int_rn(v[i].w * inv) & 255;
        xqi[t + 256 * i] = q0 | (q1 << 8) | (q2 << 16) | (q3 << 24);
    }
}

// ---------------- prepass 1b: retile xq8 row-major -> frag-tiled -------------

__global__ __launch_bounds__(256) void retile_x_kernel(
    const signed char* __restrict__ xq8, signed char* __restrict__ xqF)
{
    __shared__ __align__(16) char lds[32768];
    const int t = threadIdx.x;
    const int rb = blockIdx.x >> 2;
    const int kc = blockIdx.x & 3;

    const size_t srcBase = (size_t)rb * 32 * K_IN + (size_t)kc * 1024;
#pragma unroll
    for (int j = 0; j < 8; ++j) {
        const int u = j * 256 + t;
        const int row = u >> 6, gc = u & 63;
        const i32x4 v = *reinterpret_cast<const i32x4*>(
            xq8 + srcBase + (size_t)row * K_IN + gc * 16);
        *reinterpret_cast<i32x4*>(
            lds + ((row * 64 + (gc ^ (row & 7))) * 16)) = v;
    }
    __syncthreads();

    const int l = t & 63;
    const int W = t >> 6;
    const int row = l & 31;
    const int hi = l >> 5;
    i32x4* dst0 = reinterpret_cast<i32x4*>(xqF) +
                  ((size_t)rb * 128 + kc * 32) * 64 + l;
#pragma unroll
    for (int i = 0; i < 8; ++i) {
        const int kfl = W * 8 + i;
        const int gc = (kfl * 2 + hi) ^ (row & 7);
        const i32x4 v = *reinterpret_cast<const i32x4*>(
            lds + ((row * 64 + gc) * 16));
        dst0[(size_t)kfl * 64] = v;
    }
}

// ---------------- prepass 2: pack Wq int32 -> int8, frag-tiled ---------------

__global__ __launch_bounds__(256) void pack_w_frag_kernel(
    const int* __restrict__ wq, signed char* __restrict__ wqF)
{
    const int t = threadIdx.x;
    const int l = t & 63;
    const int W = t >> 6;
    const int rb = blockIdx.x >> 3;
    const int pc = blockIdx.x & 7;
    const int r = rb * 32 + (l & 31);
    const int4* wr4 = reinterpret_cast<const int4*>(wq) + (size_t)r * 1024;
    i32x4* outF = reinterpret_cast<i32x4*>(wqF) + (size_t)rb * 128 * 64 + l;
#pragma unroll
    for (int q = 0; q < 4; ++q) {
        const int f = W + 4 * (pc * 4 + q);
        const int c4 = f * 8 + (l >> 5) * 4;
        i32x4 o;
#pragma unroll
        for (int j = 0; j < 4; ++j) {
            const int4 a = wr4[c4 + j];
            o[j] = (a.x & 255) | ((a.y & 255) << 8) | ((a.z & 255) << 16) | ((a.w & 255) << 24);
        }
        outF[(size_t)f * 64] = o;
    }
}

// ------- int8 GEMM R16: 4-WAVE BLOCKS (256x128 tile), 2 blocks/CU ------------
// R9-R15 evidence: body = MFMA + LDS-port in SERIES; the block-wide barrier
// locks all 8 waves of the one resident block into the same phase. VGPRs cap
// the CU at 2 waves/SIMD TOTAL -- but that allows 2 x 4-wave BLOCKS instead
// of 1 x 8-wave block. Two independent barrier domains per CU desynchronize
// naturally -> block A's MFMA phase covers block B's LDS phase (m114).
// Block: 256 thr = 4 waves (2 wr x 2 wc); wave = 128x64 out = acc[4][2]
// (unchanged). Tile 256x128, BK=32, ring-4, LDS = 48KB (2/CU <= 160KB).
// Per body T: entry lgkm(2) -> CL4a; RD6(T+1) + stage(T+3) [3 glds];
// lgkm(6) -> CL4b; boundary vmcnt(3) [confirms stage(T+2) for body T+1's
// RD6(T+2); leaves stage(T+3)]; barrier. Prologue: stage 0,1,2 (9 glds),
// vmcnt(3) confirms 0 AND 1 (body 0 reads tile 1). Tail: VM=0 at T=125,126.
// WAR: stage(T+3) -> slot (T-1)&3; tile T-1 reads drained by body T-1's
// lgkm(6) + its barrier. Race-audited.

#define NKT 128            // K tiles of 32
#define SLOTA 8192         // 8 A frags x 1KB (256 rows)
#define SLOTB 4096         // 4 B frags x 1KB (128 rows)

#define MFMA(a, b, c) c = __builtin_amdgcn_mfma_i32_32x32x32_i8(a, b, c, 0, 0, 0)

// 6 reads, order: B0,B1 (cluster1), A0,A1 (cluster1), A2,A3 (cluster2)
#define RD6(P, aA, bA)                          \
    P##_B0 = dsri<0>(bA);                       \
    P##_B1 = dsri<1024>(bA);                    \
    P##_A0 = dsri<0>(aA);                       \
    P##_A1 = dsri<1024>(aA);                    \
    P##_A2 = dsri<2048>(aA);                    \
    P##_A3 = dsri<3072>(aA);

#define CL4a(P)                                               \
    MFMA(P##_A0, P##_B0, acc00); MFMA(P##_A0, P##_B1, acc01); \
    MFMA(P##_A1, P##_B0, acc10); MFMA(P##_A1, P##_B1, acc11);

#define CL4b(P)                                               \
    MFMA(P##_A2, P##_B0, acc20); MFMA(P##_A2, P##_B1, acc21); \
    MFMA(P##_A3, P##_B0, acc30); MFMA(P##_A3, P##_B1, acc31);

#define GBODY(T, C, N, DO_STAGE, VM)                                      \
    {                                                                     \
        asm volatile("s_waitcnt lgkmcnt(2)" ::: "memory");                \
        __builtin_amdgcn_sched_barrier(0);                                \
        __builtin_amdgcn_s_setprio(1);                                    \
        CL4a(C)                                                           \
        __builtin_amdgcn_s_setprio(0);                                    \
        __builtin_amdgcn_sched_barrier(0);                                \
        const unsigned aN_ = aBase + (unsigned)((((T) + 1) & 3) * SLOTA); \
        const unsigned bN_ = bBase + (unsigned)((((T) + 1) & 3) * SLOTB); \
        RD6(N, aN_, bN_)                                                  \
        if (DO_STAGE) stageAB((T) + 3);                                   \
        asm volatile("s_waitcnt lgkmcnt(6)" ::: "memory");                \
        __builtin_amdgcn_sched_barrier(0);                                \
        __builtin_amdgcn_s_setprio(1);                                    \
        CL4b(C)                                                           \
        __builtin_amdgcn_s_setprio(0);                                    \
        __builtin_amdgcn_sched_barrier(0);                                \
        asm volatile("s_waitcnt vmcnt(" #VM ")" ::: "memory");            \
        __builtin_amdgcn_sched_barrier(0);                                \
        __builtin_amdgcn_s_barrier();                                     \
        __builtin_amdgcn_sched_barrier(0);                                \
    }

#define GFINAL(C)                                                         \
    {                                                                     \
        asm volatile("s_waitcnt lgkmcnt(2)" ::: "memory");                \
        __builtin_amdgcn_sched_barrier(0);                                \
        __builtin_amdgcn_s_setprio(1);                                    \
        CL4a(C)                                                           \
        __builtin_amdgcn_s_setprio(0);                                    \
        asm volatile("s_waitcnt lgkmcnt(0)" ::: "memory");                \
        __builtin_amdgcn_sched_barrier(0);                                \
        __builtin_amdgcn_s_setprio(1);                                    \
        CL4b(C)                                                           \
        __builtin_amdgcn_s_setprio(0);                                    \
        __builtin_amdgcn_sched_barrier(0);                                \
    }

__global__ __launch_bounds__(256, 2) void qgemm_i8w4_kernel(
    const signed char* __restrict__ xqF,
    const signed char* __restrict__ wqF,
    const float* __restrict__ tok_scale,
    const float* __restrict__ row_scales,
    const float* __restrict__ bias,
    float* __restrict__ out)
{
    __shared__ __align__(16) char smem[49152];  // A [0,32K): 4 x 8KB; B [32K,48K): 4 x 4KB

    const int tid = threadIdx.x;
    const int l = tid & 63;
    const int w = tid >> 6;      // 0..3
    const int wr = w >> 1;       // 0..1
    const int wc = w & 1;        // 0..1

    // XCD-aware bijective swizzle (nwg = 1024, 1024 % 8 == 0)
    const int bid = blockIdx.x;
    const int swz = (bid & 7) * 128 + (bid >> 3);
    const int bm = swz >> 5;     // 0..31
    const int bn = swz & 31;     // 0..31

    // ---- staging: wave w stages A frags {2w,2w+1} and B frag {w} ----
    // frag-tiled global: frag (rb, kf) at (rb*128 + kf)*1024 + lane*16.
    const signed char* aS0 = xqF + ((size_t)(bm * 8 + 2 * w) * 128) * 1024 + (size_t)l * 16;
    const signed char* bS  = wqF + ((size_t)(bn * 4 + w) * 128) * 1024 + (size_t)l * 16;
    char* aDst = smem + w * 2048;              // frags 2w, 2w+1 of each slot
    char* bDst = smem + 32768 + w * 1024;      // frag w of each slot

    auto stageAB = [&](int tt) {
        const unsigned sa = (tt & 3) * SLOTA;
        const unsigned sb = (tt & 3) * SLOTB;
        __builtin_amdgcn_global_load_lds(
            (const AS1 void*)(aS0 + (size_t)tt * 1024),
            (AS3 void*)(aDst + sa), 16, 0, 0);
        __builtin_amdgcn_global_load_lds(
            (const AS1 void*)(aS0 + 131072 + (size_t)tt * 1024),   // frag rb+1
            (AS3 void*)(aDst + sa + 1024), 16, 0, 0);
        __builtin_amdgcn_global_load_lds(
            (const AS1 void*)(bS + (size_t)tt * 1024),
            (AS3 void*)(bDst + sb), 16, 0, 0);
    };

    // ---- fragment-linear ds_read bases ----
    // A: wave wr reads frags wr*4 + mb at (wr*4+mb)*1024 within the slot.
    // B: wave wc reads frags wc*2 + nb at (wc*2+nb)*1024 within the slot.
    const unsigned sbase = (unsigned)(uintptr_t)(AS3 char*)smem;
    const unsigned aBase = sbase + (unsigned)(wr * 4096 + l * 16);            // + slot*8KB + mb*1024
    const unsigned bBase = sbase + 32768u + (unsigned)(wc * 2048 + l * 16);   // + slot*4KB + nb*1024

    i32x16 acc00 = {0}, acc01 = {0}, acc10 = {0}, acc11 = {0};
    i32x16 acc20 = {0}, acc21 = {0}, acc30 = {0}, acc31 = {0};

    i32x4 X_A0, X_A1, X_A2, X_A3, X_B0, X_B1;
    i32x4 Y_A0, Y_A1, Y_A2, Y_A3, Y_B0, Y_B1;

    // ---- prologue: stage tiles 0,1,2 (9 glds); vmcnt(3) confirms tiles 0,1 ----
    stageAB(0); stageAB(1); stageAB(2);
    asm volatile("s_waitcnt vmcnt(3)" ::: "memory");
    __builtin_amdgcn_sched_barrier(0);
    __builtin_amdgcn_s_barrier();
    __builtin_amdgcn_sched_barrier(0);
    RD6(X, aBase, bBase)

    // ---- main loop: bodies 0..124 (VM=3), 125..126 (VM=0), 127 = final ----
    for (int t = 0; t < 124; t += 2) {
        GBODY(t,     X, Y, true, 3);
        GBODY(t + 1, Y, X, true, 3);
    }
    GBODY(124, X, Y, true, 3);    // stages tile 127 (the last)
    GBODY(125, Y, X, false, 0);
    GBODY(126, X, Y, false, 0);
    GFINAL(Y)

    // ---- epilogue: dequant (tok_scale via global, L2-hot), store ----
    const int cl = l & 31;
    const int rg4 = (l >> 5) * 4;
    const int gcol0 = bn * 128 + wc * 64;
    const float* tsrow = tok_scale + bm * 256 + wr * 128;
    float cs[2], bb[2];
#pragma unroll
    for (int nb = 0; nb < 2; ++nb) {
        const int col = gcol0 + nb * 32 + cl;
        cs[nb] = row_scales[col] * (1.0f / 127.0f);
        bb[nb] = bias[col];
    }
    const i32x16* accs[4][2] = {{&acc00, &acc01}, {&acc10, &acc11},
                                {&acc20, &acc21}, {&acc30, &acc31}};
#pragma unroll
    for (int mb = 0; mb < 4; ++mb) {
#pragma unroll
        for (int reg = 0; reg < 16; ++reg) {
            const int rl = mb * 32 + (reg & 3) + 8 * (reg >> 2) + rg4;
            const float tsv = tsrow[rl];
            float* orow = out + (size_t)(bm * 256 + wr * 128 + rl) * N_OUT + gcol0 + cl;
#pragma unroll
            for (int nb = 0; nb < 2; ++nb) {
                const int a = (*accs[mb][nb])[reg];
                orow[nb * 32] = (float)a * tsv * cs[nb] + bb[nb];
            }
        }
    }
}

// ---------------- launch ----------------

extern "C" void kernel_launch(void* const* d_in, const int* in_sizes, int n_in,
                              void* d_out, int out_size, void* d_ws, size_t ws_size,
                              hipStream_t stream) {
    const float* x = (const float*)d_in[0];
    const int* wq = (const int*)d_in[1];
    const float* row_scales = (const float*)d_in[2];
    const float* bias = (const float*)d_in[3];
    float* out = (float*)d_out;

    signed char* xq8 = (signed char*)d_ws;                       // 32 MiB row-major
    signed char* xqF = xq8 + (size_t)M_TOK * K_IN;               // 32 MiB frag-tiled
    signed char* wqF = xqF + (size_t)M_TOK * K_IN;               // 16 MiB frag-tiled
    float* tok_scale = (float*)(wqF + (size_t)N_OUT * K_IN);     // 32 KiB
    (void)ws_size;

    quant_x_kernel<<<M_TOK, 256, 0, stream>>>(x, xq8, tok_scale);
    pack_w_frag_kernel<<<1024, 256, 0, stream>>>(wq, wqF);
    retile_x_kernel<<<1024, 256, 0, stream>>>(xq8, xqF);

    const int nblocks = (M_TOK / 256) * (N_OUT / 128);  // 1024
    qgemm_i8w4_kernel<<<nblocks, 256, 0, stream>>>(
        xqF, wqF, tok_scale, row_scales, bias, out);
}